// Round 2
// baseline (353.743 us; speedup 1.0000x reference)
//
#include <hip/hip_runtime.h>
#include <cmath>

#define HH 96
#define WW 96
#define NPIX (HH * WW)
#define COEF 5.0f
#define BIGV 1.0e9f

// Kernel 1: per-pixel flat_ computation + init dmax slot.
__global__ void k_flat(const float* __restrict__ img,
                       const float* __restrict__ thre,
                       const float* __restrict__ add,
                       float* __restrict__ flat_out,   // ws[0..NPIX)
                       float* __restrict__ dmax_slot)  // ws[NPIX]
{
    int t = blockIdx.x * blockDim.x + threadIdx.x;
    if (t == 0) *dmax_slot = 0.0f;  // int bits of 0.0f are 0
    if (t >= NPIX) return;
    int i = t / WW, j = t % WW;
    float v  = img[t];
    float th = thre[t];
    bool high = (v >= th);

    // 5x5 local max over "low" pixels (img < thre); 0 if none in window
    float mx = -BIGV;
    for (int di = -2; di <= 2; ++di) {
        int ni = i + di;
        if (ni < 0 || ni >= HH) continue;
        for (int dj = -2; dj <= 2; ++dj) {
            int nj = j + dj;
            if (nj < 0 || nj >= WW) continue;
            int n = ni * WW + nj;
            float nv = img[n];
            if (nv < thre[n]) mx = fmaxf(mx, nv);
        }
    }
    float maxlim = (mx <= -BIGV * 0.5f) ? 0.0f : mx;

    // 3x3 local min over "high" pixels (img >= thre); 0 if none in window
    float mn = BIGV;
    for (int di = -1; di <= 1; ++di) {
        int ni = i + di;
        if (ni < 0 || ni >= HH) continue;
        for (int dj = -1; dj <= 1; ++dj) {
            int nj = j + dj;
            if (nj < 0 || nj >= WW) continue;
            int n = ni * WW + nj;
            float nv = img[n];
            if (nv >= thre[n]) mn = fminf(mn, nv);
        }
    }
    float minlim = (mn >= BIGV * 0.5f) ? 0.0f : mn;

    float img_high = high ? v : 0.0f;
    float img_low  = high ? 0.0f : v;
    float ih = (img_high - minlim) / (1.0f - minlim + 1e-11f);
    float il = img_low / (maxlim + 1e-11f);
    flat_out[t] = ih + il + (high ? add[t] : 0.0f);
}

// Kernel 2: max over all edges of |flat_[r] - flat_[c]|
__global__ void k_dmax(const float* __restrict__ flat_, float* dmax_slot)
{
    int t = blockIdx.x * blockDim.x + threadIdx.x;
    float d = 0.0f;
    if (t < NPIX) {
        int i = t / WW, j = t % WW;
        float fc = flat_[t];
        if (j + 1 < WW) d = fmaxf(d, fabsf(fc - flat_[t + 1]));
        if (i + 1 < HH) d = fmaxf(d, fabsf(fc - flat_[t + WW]));
    }
    for (int off = 32; off > 0; off >>= 1)
        d = fmaxf(d, __shfl_down(d, off, 64));
    if ((threadIdx.x & 63) == 0)
        atomicMax((int*)dmax_slot, __float_as_int(d));  // d >= 0: int-bit order ok
}

// Kernel 3 (fused): one block per row. Stream zeros for the whole row,
// then inject the <=4 nonzero entries (total_e / row_sum) into the
// still-L2-dirty lines. The total.max() normalization cancels exactly
// between weights and row_sum, so only dmax (of |diff|) is needed.
__global__ void __launch_bounds__(256) k_row(const float* __restrict__ flat_,
                                             const float* __restrict__ dmax_slot,
                                             float4* __restrict__ out4)
{
    int r = blockIdx.x;
    int tid = threadIdx.x;
    __shared__ float s_tot[4];
    __shared__ int   s_col[4];
    __shared__ float s_invrs;

    if (tid < 4) {
        int i = r / WW, j = r % WW;
        const int off[4] = {-WW, WW, -1, 1};
        bool ok = (tid == 0) ? (i > 0)
                : (tid == 1) ? (i < HH - 1)
                : (tid == 2) ? (j > 0)
                             : (j < WW - 1);
        float tot = 0.0f;
        int   col = -1;
        if (ok) {
            int n = r + off[tid];
            float d = fabsf(flat_[r] - flat_[n]);
            float inv_d = 1.0f / (*dmax_slot + 1e-11f);
            tot = expf(-COEF) + expf(-COEF * d * inv_d);  // spatial dist == 1 always
            col = n;
        }
        s_tot[tid] = tot;
        s_col[tid] = col;
    }
    __syncthreads();
    if (tid == 0) {
        float rs = s_tot[0] + s_tot[1] + s_tot[2] + s_tot[3];
        s_invrs = 1.0f / rs;  // >= 2*exp(-5) > 0 always
    }

    // stream zeros: 2304 float4 per row, 9 per thread, coalesced
    float4 z = make_float4(0.0f, 0.0f, 0.0f, 0.0f);
    float4* row = out4 + (size_t)r * (NPIX / 4);
    #pragma unroll
    for (int k = 0; k < 9; ++k)
        row[tid + k * 256] = z;

    __syncthreads();  // drains vmcnt: zero stores complete before value stores

    if (tid < 4 && s_col[tid] >= 0)
        ((float*)row)[s_col[tid]] = s_tot[tid] * s_invrs;
}

extern "C" void kernel_launch(void* const* d_in, const int* in_sizes, int n_in,
                              void* d_out, int out_size, void* d_ws, size_t ws_size,
                              hipStream_t stream)
{
    const float* img  = (const float*)d_in[0];
    const float* thre = (const float*)d_in[1];
    const float* add  = (const float*)d_in[2];
    float* out = (float*)d_out;
    float* ws  = (float*)d_ws;

    float* flat_ = ws;           // NPIX floats
    float* dmax  = ws + NPIX;    // 1 float

    const int tpb = 256;
    const int pix_blocks = (NPIX + tpb - 1) / tpb;

    k_flat<<<pix_blocks, tpb, 0, stream>>>(img, thre, add, flat_, dmax);
    k_dmax<<<pix_blocks, tpb, 0, stream>>>(flat_, dmax);
    k_row<<<NPIX, tpb, 0, stream>>>(flat_, dmax, (float4*)out);
}